// Round 5
// baseline (240.973 us; speedup 1.0000x reference)
//
#include <hip/hip_runtime.h>
#include <hip/hip_fp16.h>
#include <cstddef>
#include <cstdint>

#define DIM 128
#define SEQ 2048
#define NB 32
#define NCH 512
#define NROWS (NB * SEQ)          // 65536

typedef _Float16 half8 __attribute__((ext_vector_type(8)));
typedef float    f32x4 __attribute__((ext_vector_type(4)));

// ws layout: cmb fp16 [NROWS][NCH] | Wfg fp16 frag-linear [65536] | xh fp16 [NROWS*DIM]
#define CMB_BYTES ((size_t)NROWS * NCH * 2)       // 67,108,864
#define WFG_OFF   CMB_BYTES
#define WFG_BYTES ((size_t)NCH * DIM * 2)         // 131,072
#define XH_OFF    (WFG_OFF + WFG_BYTES)
#define XH_BYTES  ((size_t)NROWS * DIM * 2)       // 16,777,216
#define WS_NEEDED (XH_OFF + XH_BYTES)             // ~84 MB

__device__ __forceinline__ float sigf(float v) {
    return 1.0f / (1.0f + __expf(-v));
}

// ---------------------------------------------------------------------------
// k0: (blocks 0..4095) xh = fp16(x);  (blocks 4096..4127) Wfg swizzle.
// ---------------------------------------------------------------------------
__global__ void k0_prep(const float* __restrict__ x, const float* __restrict__ Wf,
                        _Float16* __restrict__ xh, _Float16* __restrict__ Wfg) {
    int bid = blockIdx.x;
    if (bid < 4096) {
        int g = bid * 256 + threadIdx.x;       // 1,048,576 threads x 8 elems
        const float* src = x + (size_t)g * 8;
        float4 v0 = *(const float4*)src;
        float4 v1 = *(const float4*)(src + 4);
        half8 hv;
        hv[0] = (_Float16)v0.x; hv[1] = (_Float16)v0.y;
        hv[2] = (_Float16)v0.z; hv[3] = (_Float16)v0.w;
        hv[4] = (_Float16)v1.x; hv[5] = (_Float16)v1.y;
        hv[6] = (_Float16)v1.z; hv[7] = (_Float16)v1.w;
        *(half8*)(xh + (size_t)g * 8) = hv;
    } else {
        int t = (bid - 4096) * 256 + threadIdx.x;   // 8192 threads x 8 elems
#pragma unroll
        for (int i = 0; i < 8; ++i) {
            int o = t * 8 + i;                       // 65536 total
            int j    = o & 7;
            int lane = (o >> 3) & 63;
            int q    = lane >> 4, n16 = lane & 15;
            int ct   = (o >> 9) & 7;
            int ks   = (o >> 12) & 1;
            int kb   = o >> 13;
            int k = kb * 64 + ks * 32 + q * 8 + j;
            int n = ct * 16 + n16;
            Wfg[o] = (_Float16)Wf[n * NCH + k];
        }
    }
}

// ---------------------------------------------------------------------------
// kfused v4: block = (batch b, 32-channel group).
//   A-frags straight from global xh (frag layout == row-major rows), prefetched
//   one tile ahead. B-frags in LDS (16 KB, staged once, frag-linear).
//   3 barriers/tile: seg -> scan -> hbuf. ~28 KB LDS, 4+ blocks/CU.
// ---------------------------------------------------------------------------
__global__ __launch_bounds__(256, 4) void kfused(
        const _Float16* __restrict__ xh,
        const float* __restrict__ Wa_u, const float* __restrict__ ba_u,
        const float* __restrict__ Wi_u, const float* __restrict__ bi_u,
        const float* __restrict__ g_u,
        const float* __restrict__ Wa_w, const float* __restrict__ ba_w,
        const float* __restrict__ Wi_w, const float* __restrict__ bi_w,
        const float* __restrict__ g_w,
        _Float16* __restrict__ cmb) {
    __shared__ _Float16 Bs[8192];        // [ks(4)][nt(4)][lane(64)][8]
    __shared__ float2   seg[16][33];
    __shared__ float    pref[16][33];
    __shared__ float    carry[32];
    __shared__ _Float16 hbuf[64][40];

    const int tid  = threadIdx.x;
    const int lane = tid & 63;
    const int w    = tid >> 6;
    const int quad = lane >> 4;
    const int n16  = lane & 15;

    const int b  = blockIdx.x;           // 0..31
    const int cg = blockIdx.y;           // 0..15
    const int p  = cg >> 3;
    const int ebase = (cg & 7) * 32;

    const float* Wa  = p ? Wa_w : Wa_u;
    const float* Wi  = p ? Wi_w : Wi_u;
    const float* bap = p ? ba_w : ba_u;
    const float* bip = p ? bi_w : bi_u;
    const float* gp  = p ? g_w  : g_u;

    // ---- stage Bs once: slot sl = ks*256 + nt*64 + l ----
    for (int sl = tid; sl < 1024; sl += 256) {
        int l  = sl & 63;
        int nt = (sl >> 6) & 3;
        int ks = sl >> 8;
        int qq = l >> 4, nn = l & 15;
        int e = ebase + (nt & 1) * 16 + nn;
        const float* Wp = (nt >> 1) ? Wi : Wa;
        const float* src = Wp + (size_t)e * DIM + ks * 32 + qq * 8;
        float4 v0 = *(const float4*)src;
        float4 v1 = *(const float4*)(src + 4);
        half8 hv;
        hv[0] = (_Float16)v0.x; hv[1] = (_Float16)v0.y;
        hv[2] = (_Float16)v0.z; hv[3] = (_Float16)v0.w;
        hv[4] = (_Float16)v1.x; hv[5] = (_Float16)v1.y;
        hv[6] = (_Float16)v1.z; hv[7] = (_Float16)v1.w;
        *(half8*)&Bs[sl * 8] = hv;
    }

    float rba[2], rbi[2], ral[2];
#pragma unroll
    for (int hh = 0; hh < 2; ++hh) {
        int e = ebase + hh * 16 + n16;
        rba[hh] = bap[e];
        rbi[hh] = bip[e];
        ral[hh] = sigf(gp[e]);
    }
    if (tid < 32) carry[tid] = 0.0f;

    // incremental recency weight: sc(s) = exp(3s/2047)
    float scb = __expf((float)(w * 16 + quad * 4) * (3.0f / 2047.0f));
    const float r1   = __expf(3.0f / 2047.0f);
    const float r2   = r1 * r1;
    const float r3   = r2 * r1;
    const float cs64 = __expf(64.0f * 3.0f / 2047.0f);

    const _Float16* xrow = xh + (size_t)b * SEQ * DIM;
    _Float16* cmbb = cmb + (size_t)b * SEQ * NCH + cg * 32;

    __syncthreads();

    // preload A-frags for tile 0
    half8 af[4];
    {
        const _Float16* ab = xrow + (size_t)(w * 16 + n16) * DIM + quad * 8;
#pragma unroll
        for (int ks = 0; ks < 4; ++ks) af[ks] = *(const half8*)(ab + ks * 32);
    }

    for (int t = 0; t < 32; ++t) {
        const int s0 = t * 64;

        // ---- MFMA: C[s = w*16+quad*4+reg][nt-tile], K=128 ----
        f32x4 acc[4];
#pragma unroll
        for (int nt = 0; nt < 4; ++nt) acc[nt] = (f32x4){0.f, 0.f, 0.f, 0.f};
#pragma unroll
        for (int ks = 0; ks < 4; ++ks) {
            half8 a = af[ks];
#pragma unroll
            for (int nt = 0; nt < 4; ++nt) {
                half8 bb = *(const half8*)&Bs[(ks * 256 + nt * 64 + lane) * 8];
                acc[nt] = __builtin_amdgcn_mfma_f32_16x16x32_f16(a, bb, acc[nt], 0, 0, 0);
            }
        }

        // ---- prefetch next tile's A-frags (wraps at t=31; harmless) ----
        {
            int tn = (t + 1) & 31;
            const _Float16* ab = xrow + (size_t)(tn * 64 + w * 16 + n16) * DIM + quad * 8;
#pragma unroll
            for (int ks = 0; ks < 4; ++ks) af[ks] = *(const half8*)(ab + ks * 32);
        }

        // ---- gates + 4-step affine compose ----
        float sc[4];
        if (p) { sc[0] = scb; sc[1] = scb * r1; sc[2] = scb * r2; sc[3] = scb * r3; }
        else   { sc[0] = sc[1] = sc[2] = sc[3] = 1.0f; }
        scb *= cs64;

        float a_s[2][4], u_s[2][4];
#pragma unroll
        for (int hh = 0; hh < 2; ++hh) {
            float A4 = 1.0f, U4 = 0.0f;
#pragma unroll
            for (int reg = 0; reg < 4; ++reg) {
                float pa = fmaf(acc[hh][reg],     sc[reg], rba[hh]);
                float pi = fmaf(acc[2 + hh][reg], sc[reg], rbi[hh]);
                float rst = sigf(pa);
                float ig  = sigf(pi);
                float a   = ral[hh] * exp2f(-rst * 1.5849625007211562f);  // alpha*3^-rst
                float u   = sqrtf(fmaxf(1.0f - a * a, 0.0f)) * ig * pi;
                a_s[hh][reg] = a; u_s[hh][reg] = u;
                A4 *= a;
                U4 = fmaf(a, U4, u);
            }
            seg[w * 4 + quad][hh * 16 + n16] = make_float2(A4, U4);
        }
        __syncthreads();

        // ---- serial inter-segment scan (16 segments, lane = channel) ----
        if (tid < 32) {
            float H = carry[tid];
#pragma unroll
            for (int ts = 0; ts < 16; ++ts) {
                float2 AU = seg[ts][tid];
                pref[ts][tid] = H;
                H = fmaf(AU.x, H, AU.y);
            }
            carry[tid] = H;
        }
        __syncthreads();

        // ---- replay with incoming h -> hbuf ----
#pragma unroll
        for (int hh = 0; hh < 2; ++hh) {
            float h = pref[w * 4 + quad][hh * 16 + n16];
#pragma unroll
            for (int reg = 0; reg < 4; ++reg) {
                h = fmaf(a_s[hh][reg], h, u_s[hh][reg]);
                hbuf[w * 16 + quad * 4 + reg][hh * 16 + n16] = (_Float16)h;
            }
        }
        __syncthreads();

        // ---- coalesced cmb store: 64 rows x 32 halfs ----
        {
            int row = tid >> 2, part = tid & 3;
            half8 hv = *(const half8*)&hbuf[row][part * 8];
            *(half8*)(cmbb + (size_t)(s0 + row) * NCH + part * 8) = hv;
        }
        // next tile's first LDS write (seg) is 1 barrier away; hbuf reads are
        // drained by the compiler's waitcnt before that s_barrier.
    }
}

// ---------------------------------------------------------------------------
// k3 v2: out = cmb(fp16) @ Wf^T(fp16) + bf via mfma_f32_16x16x32_f16.
//   K-chunks of 32 (16 KB LDS), global->reg prefetch of next chunk so VMEM
//   stays in flight across the barrier. 4+ blocks/CU.
// ---------------------------------------------------------------------------
__global__ __launch_bounds__(256, 4) void k3_mfma(
        const _Float16* __restrict__ cmb, const _Float16* __restrict__ Wfg,
        const float* __restrict__ bfv, float* __restrict__ out) {
    __shared__ _Float16 As[4096];   // 8 pages (rt) x [k8*16+m] x 8
    __shared__ _Float16 Bs[4096];   // 8 pages (ct) x [lane] x 8

    const int tid  = threadIdx.x;
    const int lane = tid & 63;
    const int w    = tid >> 6;
    const int row0 = blockIdx.x * 128;
    const int q    = lane >> 4;
    const int nn   = lane & 15;

    f32x4 acc[2][8];
#pragma unroll
    for (int rt = 0; rt < 2; ++rt)
#pragma unroll
        for (int ct = 0; ct < 8; ++ct)
            acc[rt][ct] = (f32x4){0.0f, 0.0f, 0.0f, 0.0f};

    // staging descriptors (2 granules each for A and B per thread)
    int fa[2], ra[2], k8a[2];
#pragma unroll
    for (int i = 0; i < 2; ++i) {
        fa[i]  = tid + i * 256;
        ra[i]  = fa[i] >> 2;
        k8a[i] = fa[i] & 3;
    }

    uint4 pa[2], pb[2];
    // preload chunk 0
#pragma unroll
    for (int i = 0; i < 2; ++i) {
        pa[i] = *(const uint4*)(cmb + (size_t)(row0 + ra[i]) * NCH + k8a[i] * 8);
        pb[i] = *(const uint4*)(Wfg + (size_t)fa[i] * 8);
    }

    for (int kb2 = 0; kb2 < 16; ++kb2) {
        // ---- regs -> LDS ----
#pragma unroll
        for (int i = 0; i < 2; ++i) {
            *(uint4*)&As[(((ra[i] >> 4) * 64) + k8a[i] * 16 + (ra[i] & 15)) * 8] = pa[i];
            *(uint4*)&Bs[(size_t)fa[i] * 8] = pb[i];
        }
        __syncthreads();

        // ---- prefetch next chunk (VMEM overlaps MFMA below) ----
        if (kb2 < 15) {
            int kc = (kb2 + 1) * 32;
#pragma unroll
            for (int i = 0; i < 2; ++i) {
                pa[i] = *(const uint4*)(cmb + (size_t)(row0 + ra[i]) * NCH + kc + k8a[i] * 8);
                pb[i] = *(const uint4*)(Wfg + (size_t)(kb2 + 1) * 4096 + (size_t)fa[i] * 8);
            }
        }

        // ---- MFMA ----
        half8 a0 = *(const half8*)&As[((w * 2 + 0) * 64 + lane) * 8];
        half8 a1 = *(const half8*)&As[((w * 2 + 1) * 64 + lane) * 8];
#pragma unroll
        for (int ct = 0; ct < 8; ++ct) {
            half8 bb = *(const half8*)&Bs[(ct * 64 + lane) * 8];
            acc[0][ct] = __builtin_amdgcn_mfma_f32_16x16x32_f16(a0, bb, acc[0][ct], 0, 0, 0);
            acc[1][ct] = __builtin_amdgcn_mfma_f32_16x16x32_f16(a1, bb, acc[1][ct], 0, 0, 0);
        }
        __syncthreads();
    }

    // epilogue: C/D layout col = lane&15, row = quad*4 + reg
#pragma unroll
    for (int rt = 0; rt < 2; ++rt) {
        int rbase = row0 + w * 32 + rt * 16 + q * 4;
#pragma unroll
        for (int ct = 0; ct < 8; ++ct) {
            int col = ct * 16 + nn;
            float bias = bfv[col];
#pragma unroll
            for (int reg = 0; reg < 4; ++reg)
                out[(size_t)(rbase + reg) * DIM + col] = acc[rt][ct][reg] + bias;
        }
    }
}

// ---------------------------------------------------------------------------
extern "C" void kernel_launch(void* const* d_in, const int* in_sizes, int n_in,
                              void* d_out, int out_size, void* d_ws, size_t ws_size,
                              hipStream_t stream) {
    if (ws_size < WS_NEEDED) return;

    const float* x    = (const float*)d_in[0];
    const float* Wa_u = (const float*)d_in[1];
    const float* ba_u = (const float*)d_in[2];
    const float* Wi_u = (const float*)d_in[3];
    const float* bi_u = (const float*)d_in[4];
    const float* g_u  = (const float*)d_in[5];
    const float* Wa_w = (const float*)d_in[6];
    const float* ba_w = (const float*)d_in[7];
    const float* Wi_w = (const float*)d_in[8];
    const float* bi_w = (const float*)d_in[9];
    const float* g_w  = (const float*)d_in[10];
    const float* Wf   = (const float*)d_in[11];
    const float* bfv  = (const float*)d_in[12];
    float* out = (float*)d_out;

    char* ws = (char*)d_ws;
    _Float16* cmb = (_Float16*)ws;
    _Float16* Wfg = (_Float16*)(ws + WFG_OFF);
    _Float16* xh  = (_Float16*)(ws + XH_OFF);

    hipLaunchKernelGGL(k0_prep, dim3(4128), dim3(256), 0, stream, x, Wf, xh, Wfg);
    hipLaunchKernelGGL(kfused, dim3(32, 16), dim3(256), 0, stream,
                       xh, Wa_u, ba_u, Wi_u, bi_u, g_u,
                       Wa_w, ba_w, Wi_w, bi_w, g_w, cmb);
    hipLaunchKernelGGL(k3_mfma, dim3(512), dim3(256), 0, stream,
                       cmb, Wfg, bfv, out);
}

// Round 6
// 203.467 us; speedup vs baseline: 1.1843x; 1.1843x over previous
//
#include <hip/hip_runtime.h>
#include <hip/hip_fp16.h>
#include <cstddef>
#include <cstdint>

#define DIM 128
#define SEQ 2048
#define NB 32
#define NCH 512
#define NROWS (NB * SEQ)          // 65536

typedef _Float16 half8 __attribute__((ext_vector_type(8)));
typedef float    f32x4 __attribute__((ext_vector_type(4)));

// ws layout: cmb fp16 [NROWS][NCH] | Wfg fp16 frag-linear [65536] | xh fp16 [NROWS*DIM]
#define CMB_BYTES ((size_t)NROWS * NCH * 2)       // 67,108,864
#define WFG_OFF   CMB_BYTES
#define WFG_BYTES ((size_t)NCH * DIM * 2)         // 131,072
#define XH_OFF    (WFG_OFF + WFG_BYTES)
#define XH_BYTES  ((size_t)NROWS * DIM * 2)       // 16,777,216
#define WS_NEEDED (XH_OFF + XH_BYTES)             // ~84 MB

__device__ __forceinline__ float sigf(float v) {
    return 1.0f / (1.0f + __expf(-v));
}

// ---------------------------------------------------------------------------
// k0: (blocks 0..4095) xh = fp16(x);  (blocks 4096..4127) Wfg swizzle.
// ---------------------------------------------------------------------------
__global__ void k0_prep(const float* __restrict__ x, const float* __restrict__ Wf,
                        _Float16* __restrict__ xh, _Float16* __restrict__ Wfg) {
    int bid = blockIdx.x;
    if (bid < 4096) {
        int g = bid * 256 + threadIdx.x;
        const float* src = x + (size_t)g * 8;
        float4 v0 = *(const float4*)src;
        float4 v1 = *(const float4*)(src + 4);
        half8 hv;
        hv[0] = (_Float16)v0.x; hv[1] = (_Float16)v0.y;
        hv[2] = (_Float16)v0.z; hv[3] = (_Float16)v0.w;
        hv[4] = (_Float16)v1.x; hv[5] = (_Float16)v1.y;
        hv[6] = (_Float16)v1.z; hv[7] = (_Float16)v1.w;
        *(half8*)(xh + (size_t)g * 8) = hv;
    } else {
        int t = (bid - 4096) * 256 + threadIdx.x;
#pragma unroll
        for (int i = 0; i < 8; ++i) {
            int o = t * 8 + i;
            int j    = o & 7;
            int lane = (o >> 3) & 63;
            int q    = lane >> 4, n16 = lane & 15;
            int ct   = (o >> 9) & 7;
            int ks   = (o >> 12) & 1;
            int kb   = o >> 13;
            int k = kb * 64 + ks * 32 + q * 8 + j;
            int n = ct * 16 + n16;
            Wfg[o] = (_Float16)Wf[n * NCH + k];
        }
    }
}

// ---------------------------------------------------------------------------
// kfused v5: block = (batch b, 16-channel group) -> grid 32x32 = 1024 blocks
//   (4 blocks/CU). Thread owns 1 channel x 4 contiguous s. A-frags straight
//   from global xh (prefetched 1 tile ahead); B-frags in LDS (8 KB, staged
//   once). 2 barriers/tile: seg -> scan -> replay+direct store.
// ---------------------------------------------------------------------------
__global__ __launch_bounds__(256, 4) void kfused(
        const _Float16* __restrict__ xh,
        const float* __restrict__ Wa_u, const float* __restrict__ ba_u,
        const float* __restrict__ Wi_u, const float* __restrict__ bi_u,
        const float* __restrict__ g_u,
        const float* __restrict__ Wa_w, const float* __restrict__ ba_w,
        const float* __restrict__ Wi_w, const float* __restrict__ bi_w,
        const float* __restrict__ g_w,
        _Float16* __restrict__ cmb) {
    __shared__ _Float16 Bs[4096];        // [ks(4)][nt(2)][lane(64)][8] = 8 KB
    __shared__ float2   seg[16][17];
    __shared__ float    pref[16][17];
    __shared__ float    carry[16];

    const int tid  = threadIdx.x;
    const int lane = tid & 63;
    const int w    = tid >> 6;
    const int quad = lane >> 4;
    const int n16  = lane & 15;

    const int b  = blockIdx.x;           // 0..31
    const int cg = blockIdx.y;           // 0..31
    const int p  = cg >> 4;              // path
    const int ebase = (cg & 15) * 16;    // 16 channels per block

    const float* Wa  = p ? Wa_w : Wa_u;
    const float* Wi  = p ? Wi_w : Wi_u;
    const float* bap = p ? ba_w : ba_u;
    const float* bip = p ? bi_w : bi_u;
    const float* gp  = p ? g_w  : g_u;

    // ---- stage Bs once: slot sl = ks*128 + nt*64 + l  (512 slots, 2/thread)
    for (int sl = tid; sl < 512; sl += 256) {
        int l  = sl & 63;
        int nt = (sl >> 6) & 1;          // 0 = pa (Wa), 1 = pi (Wi)
        int ks = sl >> 7;
        int qq = l >> 4, nn = l & 15;
        int e = ebase + nn;
        const float* Wp = nt ? Wi : Wa;
        const float* src = Wp + (size_t)e * DIM + ks * 32 + qq * 8;
        float4 v0 = *(const float4*)src;
        float4 v1 = *(const float4*)(src + 4);
        half8 hv;
        hv[0] = (_Float16)v0.x; hv[1] = (_Float16)v0.y;
        hv[2] = (_Float16)v0.z; hv[3] = (_Float16)v0.w;
        hv[4] = (_Float16)v1.x; hv[5] = (_Float16)v1.y;
        hv[6] = (_Float16)v1.z; hv[7] = (_Float16)v1.w;
        *(half8*)&Bs[sl * 8] = hv;
    }

    // per-thread channel params (channel cc = n16)
    const int e = ebase + n16;
    const float rba = bap[e];
    const float rbi = bip[e];
    const float ral = sigf(gp[e]);
    if (tid < 16) carry[tid] = 0.0f;

    // incremental recency weight: sc(s) = exp(3s/2047)
    float scb = __expf((float)(w * 16 + quad * 4) * (3.0f / 2047.0f));
    const float r1   = __expf(3.0f / 2047.0f);
    const float r2   = r1 * r1;
    const float r3   = r2 * r1;
    const float cs64 = __expf(64.0f * 3.0f / 2047.0f);

    const _Float16* xrow = xh + (size_t)b * SEQ * DIM;
    _Float16* cmbb = cmb + (size_t)b * SEQ * NCH + cg * 16 + n16;

    __syncthreads();

    // preload A-frags for tile 0 (A row = s-local = w*16 + n16)
    half8 af[4];
    {
        const _Float16* ab = xrow + (size_t)(w * 16 + n16) * DIM + quad * 8;
#pragma unroll
        for (int ks = 0; ks < 4; ++ks) af[ks] = *(const half8*)(ab + ks * 32);
    }

    for (int t = 0; t < 32; ++t) {
        const int s0 = t * 64;

        // ---- MFMA: C[s = w*16+quad*4+reg][nt], K=128 ----
        f32x4 acc[2];
        acc[0] = (f32x4){0.f, 0.f, 0.f, 0.f};
        acc[1] = (f32x4){0.f, 0.f, 0.f, 0.f};
#pragma unroll
        for (int ks = 0; ks < 4; ++ks) {
            half8 a = af[ks];
            half8 b0 = *(const half8*)&Bs[(ks * 128 + lane) * 8];
            half8 b1 = *(const half8*)&Bs[(ks * 128 + 64 + lane) * 8];
            acc[0] = __builtin_amdgcn_mfma_f32_16x16x32_f16(a, b0, acc[0], 0, 0, 0);
            acc[1] = __builtin_amdgcn_mfma_f32_16x16x32_f16(a, b1, acc[1], 0, 0, 0);
        }

        // ---- prefetch next tile's A-frags (wraps at t=31; harmless) ----
        {
            int tn = (t + 1) & 31;
            const _Float16* ab = xrow + (size_t)(tn * 64 + w * 16 + n16) * DIM + quad * 8;
#pragma unroll
            for (int ks = 0; ks < 4; ++ks) af[ks] = *(const half8*)(ab + ks * 32);
        }

        // ---- gates + 4-step affine compose ----
        float sc[4];
        if (p) { sc[0] = scb; sc[1] = scb * r1; sc[2] = scb * r2; sc[3] = scb * r3; }
        else   { sc[0] = sc[1] = sc[2] = sc[3] = 1.0f; }
        scb *= cs64;

        float a_s[4], u_s[4];
        float A4 = 1.0f, U4 = 0.0f;
#pragma unroll
        for (int reg = 0; reg < 4; ++reg) {
            float pa = fmaf(acc[0][reg], sc[reg], rba);
            float pi = fmaf(acc[1][reg], sc[reg], rbi);
            float rst = sigf(pa);
            float ig  = sigf(pi);
            float a   = ral * exp2f(-rst * 1.5849625007211562f);  // alpha*3^-rst
            float u   = sqrtf(fmaxf(1.0f - a * a, 0.0f)) * ig * pi;
            a_s[reg] = a; u_s[reg] = u;
            A4 *= a;
            U4 = fmaf(a, U4, u);
        }
        seg[w * 4 + quad][n16] = make_float2(A4, U4);
        __syncthreads();

        // ---- serial inter-segment scan (16 segments, lane = channel) ----
        if (tid < 16) {
            float H = carry[tid];
#pragma unroll
            for (int ts = 0; ts < 16; ++ts) {
                float2 AU = seg[ts][tid];
                pref[ts][tid] = H;
                H = fmaf(AU.x, H, AU.y);
            }
            carry[tid] = H;
        }
        __syncthreads();

        // ---- replay + direct store (2B/lane, 16-lane = 32B segments) ----
        {
            float h = pref[w * 4 + quad][n16];
            _Float16* dst = cmbb + (size_t)(s0 + w * 16 + quad * 4) * NCH;
#pragma unroll
            for (int reg = 0; reg < 4; ++reg) {
                h = fmaf(a_s[reg], h, u_s[reg]);
                dst[(size_t)reg * NCH] = (_Float16)h;
            }
        }
        // seg write of tile t+1 happens only after this thread passes the next
        // barrier-1; pref reads above complete before that in program order.
    }
}

// ---------------------------------------------------------------------------
// k3 v3: round-3 page structure (64-wide K chunks, 32 MFMA/barrier), but
//   64-row tiles -> 1024 blocks = 4 blocks/CU. LDS 8 KB As + 16 KB Bs.
// ---------------------------------------------------------------------------
__global__ __launch_bounds__(256, 4) void k3_mfma(
        const _Float16* __restrict__ cmb, const _Float16* __restrict__ Wfg,
        const float* __restrict__ bfv, float* __restrict__ out) {
    __shared__ _Float16 As[8 * 512];    // pages (mt 0..3, ks 0..1) x 512 halfs
    __shared__ _Float16 Bs[16 * 512];   // pages (ks 0..1, ct 0..7) x 512 halfs

    const int tid  = threadIdx.x;
    const int lane = tid & 63;
    const int w    = tid >> 6;          // wave = m-tile, rows w*16..+15
    const int row0 = blockIdx.x * 64;
    const int q    = lane >> 4;
    const int nn   = lane & 15;

    f32x4 acc[8];
#pragma unroll
    for (int ct = 0; ct < 8; ++ct) acc[ct] = (f32x4){0.0f, 0.0f, 0.0f, 0.0f};

    for (int kb = 0; kb < 8; ++kb) {
        const int kc = kb * 64;
        // stage A: 512 granules of 8 halfs (2/thread), coalesced global
#pragma unroll
        for (int i = 0; i < 2; ++i) {
            int f = tid + i * 256;
            int r = f >> 3, k8 = f & 7;
            uint4 v = *(const uint4*)(cmb + (size_t)(row0 + r) * NCH + kc + k8 * 8);
            int mt = r >> 4, m = r & 15, ks = k8 >> 2, qq = k8 & 3;
            *(uint4*)&As[(((mt * 2 + ks) * 64) + qq * 16 + m) * 8] = v;
        }
        // stage B: frag-linear in global; straight copy (4/thread)
#pragma unroll
        for (int i = 0; i < 4; ++i) {
            int f = tid + i * 256;
            uint4 v = *(const uint4*)(Wfg + (size_t)kb * 8192 + (size_t)f * 8);
            *(uint4*)&Bs[(size_t)f * 8] = v;
        }
        __syncthreads();

#pragma unroll
        for (int ks = 0; ks < 2; ++ks) {
            half8 a0 = *(const half8*)&As[((w * 2 + ks) * 64 + lane) * 8];
#pragma unroll
            for (int ct = 0; ct < 8; ++ct) {
                half8 bb = *(const half8*)&Bs[((ks * 8 + ct) * 64 + lane) * 8];
                acc[ct] = __builtin_amdgcn_mfma_f32_16x16x32_f16(a0, bb, acc[ct], 0, 0, 0);
            }
        }
        __syncthreads();
    }

    // epilogue: C/D layout col = lane&15, row = quad*4 + reg
    int rbase = row0 + w * 16 + q * 4;
#pragma unroll
    for (int ct = 0; ct < 8; ++ct) {
        int col = ct * 16 + nn;
        float bias = bfv[col];
#pragma unroll
        for (int reg = 0; reg < 4; ++reg)
            out[(size_t)(rbase + reg) * DIM + col] = acc[ct][reg] + bias;
    }
}

// ---------------------------------------------------------------------------
extern "C" void kernel_launch(void* const* d_in, const int* in_sizes, int n_in,
                              void* d_out, int out_size, void* d_ws, size_t ws_size,
                              hipStream_t stream) {
    if (ws_size < WS_NEEDED) return;

    const float* x    = (const float*)d_in[0];
    const float* Wa_u = (const float*)d_in[1];
    const float* ba_u = (const float*)d_in[2];
    const float* Wi_u = (const float*)d_in[3];
    const float* bi_u = (const float*)d_in[4];
    const float* g_u  = (const float*)d_in[5];
    const float* Wa_w = (const float*)d_in[6];
    const float* ba_w = (const float*)d_in[7];
    const float* Wi_w = (const float*)d_in[8];
    const float* bi_w = (const float*)d_in[9];
    const float* g_w  = (const float*)d_in[10];
    const float* Wf   = (const float*)d_in[11];
    const float* bfv  = (const float*)d_in[12];
    float* out = (float*)d_out;

    char* ws = (char*)d_ws;
    _Float16* cmb = (_Float16*)ws;
    _Float16* Wfg = (_Float16*)(ws + WFG_OFF);
    _Float16* xh  = (_Float16*)(ws + XH_OFF);

    hipLaunchKernelGGL(k0_prep, dim3(4128), dim3(256), 0, stream, x, Wf, xh, Wfg);
    hipLaunchKernelGGL(kfused, dim3(32, 32), dim3(256), 0, stream,
                       xh, Wa_u, ba_u, Wi_u, bi_u, g_u,
                       Wa_w, ba_w, Wi_w, bi_w, g_w, cmb);
    hipLaunchKernelGGL(k3_mfma, dim3(1024), dim3(256), 0, stream,
                       cmb, Wfg, bfv, out);
}